// Round 2
// baseline (597.743 us; speedup 1.0000x reference)
//
#include <hip/hip_runtime.h>

typedef unsigned short ushort_t;
typedef unsigned int uint_t;
typedef __attribute__((ext_vector_type(8))) short bf16x8;
typedef __attribute__((ext_vector_type(4))) float floatx4;

#define SEQ 2048
#define DIM 4096
#define NH 32
#define NKV 8
#define HD 128
#define KVDIM 1024
#define QKVN 6144  // DIM + 2*KVDIM

__device__ __forceinline__ ushort_t f2b(float f) {
  union { float f; uint_t u; } x; x.f = f;
  uint_t u = x.u;
  u += 0x7fffu + ((u >> 16) & 1u);  // round-to-nearest-even
  return (ushort_t)(u >> 16);
}

#define GLOAD_LDS(g, l) \
  __builtin_amdgcn_global_load_lds((const __attribute__((address_space(1))) void*)(g), \
                                   (__attribute__((address_space(3))) void*)(l), 16, 0, 0)

#define BARX() asm volatile("s_barrier" ::: "memory")
#define WAIT_VM(n) asm volatile("s_waitcnt vmcnt(" #n ")" ::: "memory")
#define LGKM0() asm volatile("s_waitcnt lgkmcnt(0)" ::: "memory")

// ---------------- all f32 -> bf16 converts in one kernel ----------------
__global__ __launch_bounds__(256) void cvt_all(const float* __restrict__ x,
                                               const float* __restrict__ wq,
                                               const float* __restrict__ wk,
                                               const float* __restrict__ wv,
                                               const float* __restrict__ wo,
                                               ushort_t* __restrict__ xb,
                                               ushort_t* __restrict__ wqkvb,
                                               ushort_t* __restrict__ wob) {
  int b = blockIdx.x;
  const float* src; ushort_t* dst; int i;
  if (b < 4096)       { src = x;  dst = xb;               i = b * 256 + threadIdx.x; }
  else if (b < 12288) { src = wq; dst = wqkvb;            i = (b - 4096) * 256 + threadIdx.x; }
  else if (b < 14336) { src = wk; dst = wqkvb + 16777216; i = (b - 12288) * 256 + threadIdx.x; }
  else if (b < 16384) { src = wv; dst = wqkvb + 20971520; i = (b - 14336) * 256 + threadIdx.x; }
  else                { src = wo; dst = wob;              i = (b - 16384) * 256 + threadIdx.x; }
  const float4* s = (const float4*)src;
  float4 a = s[2 * i], c = s[2 * i + 1];
  union { ushort_t u[8]; uint4 v; } o;
  o.u[0] = f2b(a.x); o.u[1] = f2b(a.y); o.u[2] = f2b(a.z); o.u[3] = f2b(a.w);
  o.u[4] = f2b(c.x); o.u[5] = f2b(c.y); o.u[6] = f2b(c.z); o.u[7] = f2b(c.w);
  ((uint4*)dst)[i] = o.v;
}

// ---------------- bf16 GEMM: C f32[M][N] = A[M][K] * B[N][K]^T ----------------
// BM=256, BN=128, BK=64. 512 threads = 8 waves (4M x 2N), wave tile 64x64.
// 2 phases per K-tile, 16 MFMA per phase (m201's barrier:MFMA ratio).
// LDS 96KB: double-buffered A(256x64) + B(128x64), chunk^(row&7) swizzle.
// Counted vmcnt(4) twice per 2-K-tile iteration; stages placed strictly after
// the target region's last barrier-separated read:
//   ph1u: read slot0 A(all)+B01 | stage B(v)   -> slot1-B (freed prev ph2v)
//   ph2u: read slot0 B23        | stage A(u+2) -> slot0-A (freed ph1u)   | vmcnt(4)
//   ph1v: read slot1 A(all)+B01 | stage B(u+2) -> slot0-B (freed ph2u)
//   ph2v: read slot1 B23        | stage A(v+2) -> slot1-A (freed ph1v)   | vmcnt(4)
// The lgkmcnt(0) after each mid-phase barrier guarantees every wave's ds_reads
// completed before any wave passes the closing barrier and issues stages.
__global__ __launch_bounds__(512, 2) void gemm2p(const ushort_t* __restrict__ A,
                                                 const ushort_t* __restrict__ B,
                                                 float* __restrict__ C,
                                                 int N, int K) {
  __shared__ __attribute__((aligned(16))) ushort_t sA[2][16384];  // [slot][256 rows][64]
  __shared__ __attribute__((aligned(16))) ushort_t sB[2][8192];   // [slot][128 rows][64]

  int tid = threadIdx.x;
  int lane = tid & 63;
  int w = tid >> 6;
  int wm = w >> 1, wn = w & 1;          // 4M x 2N waves
  int l15 = lane & 15, l4 = lane >> 4;
  int co0 = (l4 ^ (l15 & 7)) << 3;      // swizzled frag elem offset, ks=0
  int co1 = co0 ^ 32;                   // ks=1 (chunk^4)

  // XCD swizzle, n-major: each XCD gets all 8 m-tiles x contiguous n-tiles.
  int nblk = (int)gridDim.x;            // multiple of 8 (384 or 256)
  int lin = ((int)blockIdx.x & 7) * (nblk >> 3) + ((int)blockIdx.x >> 3);
  int m0 = (lin & 7) << 8;
  int n0 = (lin >> 3) << 7;

  int nkt = K >> 6;
  int niter = nkt >> 1;

  // staging: 1 gload/thread per 64-row unit; LDS linear, global col pre-swizzled
  int r0 = tid >> 3;
  int cg8 = ((tid & 7) ^ (r0 & 7)) << 3;
  const ushort_t* sa = A + (size_t)(m0 + r0) * K + cg8;
  const ushort_t* sb = B + (size_t)(n0 + r0) * K + cg8;
  int ldsb = (tid & ~63) << 3;          // wave-uniform elem offset within unit
  size_t rK = (size_t)64 * K;           // 64-row global stride

#define SUA(s, uu, k0) GLOAD_LDS(sa + (size_t)(uu) * rK + (k0), &sA[s][(uu) * 4096 + ldsb])
#define SUB(s, uu, k0) GLOAD_LDS(sb + (size_t)(uu) * rK + (k0), &sB[s][(uu) * 4096 + ldsb])

  floatx4 acc[4][4] = {};
  bf16x8 a[4][2], b[4][2];

#define RDA(s) do { const ushort_t* pa = &sA[s][(wm * 64 + l15) * 64]; \
  _Pragma("unroll") for (int rg = 0; rg < 4; ++rg) { \
    a[rg][0] = *(const bf16x8*)&pa[rg * 1024 + co0]; \
    a[rg][1] = *(const bf16x8*)&pa[rg * 1024 + co1]; } } while (0)
#define RDB01(s) do { const ushort_t* pb = &sB[s][(wn * 64 + l15) * 64]; \
  _Pragma("unroll") for (int cg = 0; cg < 2; ++cg) { \
    b[cg][0] = *(const bf16x8*)&pb[cg * 1024 + co0]; \
    b[cg][1] = *(const bf16x8*)&pb[cg * 1024 + co1]; } } while (0)
#define RDB23(s) do { const ushort_t* pb = &sB[s][(wn * 64 + l15) * 64]; \
  _Pragma("unroll") for (int cg = 2; cg < 4; ++cg) { \
    b[cg][0] = *(const bf16x8*)&pb[cg * 1024 + co0]; \
    b[cg][1] = *(const bf16x8*)&pb[cg * 1024 + co1]; } } while (0)

#define QUAD(CG) do { __builtin_amdgcn_s_setprio(1); \
  _Pragma("unroll") for (int rg = 0; rg < 4; ++rg) \
  _Pragma("unroll") for (int cg = CG; cg < CG + 2; ++cg) \
  _Pragma("unroll") for (int ks = 0; ks < 2; ++ks) \
    acc[rg][cg] = __builtin_amdgcn_mfma_f32_16x16x32_bf16( \
        a[rg][ks], b[cg][ks], acc[rg][cg], 0, 0, 0); \
  __builtin_amdgcn_s_setprio(0); } while (0)

  // prologue: tile0 {A,B} -> slot0 (6), tile1 {A} -> slot1 (4); wait tile0
  SUA(0, 0, 0); SUA(0, 1, 0); SUA(0, 2, 0); SUA(0, 3, 0);
  SUB(0, 0, 0); SUB(0, 1, 0);
  SUA(1, 0, 64); SUA(1, 1, 64); SUA(1, 2, 64); SUA(1, 3, 64);
  WAIT_VM(4);
  BARX();

#pragma unroll 1
  for (int i = 0; i < niter; ++i) {
    int kv = (2 * i + 1) << 6;
    int tu2 = 2 * i + 2; if (tu2 > nkt - 1) tu2 = nkt - 1;  // clamped overrun stages
    int tv2 = 2 * i + 3; if (tv2 > nkt - 1) tv2 = nkt - 1;  // land in freed regions
    int ku2 = tu2 << 6, kv2 = tv2 << 6;

    // ph1u
    RDA(0); RDB01(0);
    SUB(1, 0, kv); SUB(1, 1, kv);
    BARX(); LGKM0();
    QUAD(0);
    BARX();
    // ph2u
    RDB23(0);
    SUA(0, 0, ku2); SUA(0, 1, ku2); SUA(0, 2, ku2); SUA(0, 3, ku2);
    BARX(); LGKM0();
    QUAD(2);
    WAIT_VM(4);
    BARX();
    // ph1v
    RDA(1); RDB01(1);
    SUB(0, 0, ku2); SUB(0, 1, ku2);
    BARX(); LGKM0();
    QUAD(0);
    BARX();
    // ph2v
    RDB23(1);
    SUA(1, 0, kv2); SUA(1, 1, kv2); SUA(1, 2, kv2); SUA(1, 3, kv2);
    BARX(); LGKM0();
    QUAD(2);
    WAIT_VM(4);
    BARX();
  }

  // epilogue: C/D layout col=lane&15, row=(lane>>4)*4+reg
#pragma unroll
  for (int rg = 0; rg < 4; ++rg)
#pragma unroll
    for (int cg = 0; cg < 4; ++cg) {
      float* cp = C + (size_t)(m0 + wm * 64 + rg * 16 + l4 * 4) * N
                    + (n0 + wn * 64 + cg * 16 + l15);
#pragma unroll
      for (int r = 0; r < 4; ++r) cp[(size_t)r * N] = acc[rg][cg][r];
    }
#undef SUA
#undef SUB
#undef RDA
#undef RDB01
#undef RDB23
#undef QUAD
}

// ---------------- rope_q + rope_k + zero_tail fused (branch by block) ----------------
__global__ __launch_bounds__(256) void posteps(const float* __restrict__ qkv,
                                               const float* __restrict__ cosf,
                                               const float* __restrict__ sinf,
                                               ushort_t* __restrict__ qb,
                                               ushort_t* __restrict__ kb,
                                               float* __restrict__ out) {
  int b = blockIdx.x;
  if (b < 16384) {  // rope_q, pre-scaled by log2(e)/sqrt(128)
    const float QS = 1.4426950408889634f * 0.08838834764831845f;
    int idx = b * 256 + threadIdx.x;
    int pos = idx >> 11;
    int p = idx & 2047;
    int h = p >> 6, i = p & 63;
    size_t sb = (size_t)pos * QKVN + h * HD + 2 * i;
    float x1 = qkv[sb], x2 = qkv[sb + 1];
    float c = cosf[pos * 64 + i], s = sinf[pos * 64 + i];
    float r1 = (x1 * c - x2 * s) * QS;
    float r2 = (x1 * s + x2 * c) * QS;
    size_t db = (size_t)pos * DIM + h * HD + 2 * i;
    ((uint_t*)qb)[db >> 1] = (uint_t)f2b(r1) | ((uint_t)f2b(r2) << 16);
  } else if (b < 20480) {  // rope_k + cache_k
    int idx = (b - 16384) * 256 + threadIdx.x;
    int pos = idx >> 9;
    int p = idx & 511;
    int kvh = p >> 6, i = p & 63;
    size_t sb = (size_t)pos * QKVN + DIM + kvh * HD + 2 * i;
    float x1 = qkv[sb], x2 = qkv[sb + 1];
    float c = cosf[pos * 64 + i], s = sinf[pos * 64 + i];
    float r1 = x1 * c - x2 * s;
    float r2 = x1 * s + x2 * c;
    size_t db = (size_t)pos * KVDIM + kvh * HD + 2 * i;
    ((uint_t*)kb)[db >> 1] = (uint_t)f2b(r1) | ((uint_t)f2b(r2) << 16);
    float2 cv; cv.x = r1; cv.y = r2;
    ((float2*)(out + 8388608))[db >> 1] = cv;  // cache_k base
  } else {  // zero tails of both caches
    int i = (b - 20480) * 256 + threadIdx.x;
    float4 z = {0.f, 0.f, 0.f, 0.f};
    ((float4*)(out + 10485760))[i] = z;  // cache_k rows 2048..4095
    ((float4*)(out + 14680064))[i] = z;  // cache_v rows 2048..4095
  }
}

// ---------------- V: cache_v f32 copy + transposed bf16 Vt[kvh][d][pos] ----------------
__global__ __launch_bounds__(256) void vt_cache(const float* __restrict__ qkv,
                                                ushort_t* __restrict__ vtb,
                                                float* __restrict__ cache_v) {
  __shared__ float tile[64][65];
  int pos0 = blockIdx.x * 64, c0 = blockIdx.y * 64;
  int t = threadIdx.x;
  int pr = t >> 4, cq = (t & 15) * 4;
#pragma unroll
  for (int rr = 0; rr < 4; ++rr) {
    int prow = pr + rr * 16;
    float4 v = *(const float4*)(qkv + (size_t)(pos0 + prow) * QKVN + DIM + KVDIM + c0 + cq);
    *(float4*)(cache_v + (size_t)(pos0 + prow) * KVDIM + c0 + cq) = v;
    tile[prow][cq] = v.x; tile[prow][cq + 1] = v.y;
    tile[prow][cq + 2] = v.z; tile[prow][cq + 3] = v.w;
  }
  __syncthreads();
  int dc = t >> 2, pg = (t & 3) * 16;
  int kvh = c0 >> 7, dl = (c0 & 127) + dc;
  union { ushort_t u[16]; uint4 q[2]; } o;
#pragma unroll
  for (int e = 0; e < 16; ++e) o.u[e] = f2b(tile[pg + e][dc]);
  uint4* dst = (uint4*)(vtb + (size_t)kvh * (HD * SEQ) + (size_t)dl * SEQ + pos0 + pg);
  dst[0] = o.q[0]; dst[1] = o.q[1];
}

// ---------------- flash attention: causal, GQA 4:1, pair-balanced ----------------
__global__ __launch_bounds__(256) void attn(const ushort_t* __restrict__ Q,
                                            const ushort_t* __restrict__ Kb,
                                            const ushort_t* __restrict__ Vt,
                                            ushort_t* __restrict__ O) {
  int h = blockIdx.y;
  int kvh = h >> 2;
  int tid = threadIdx.x;
  int w = tid >> 6, lane = tid & 63;
  int row = lane & 15, quad = lane >> 4;

  __shared__ __attribute__((aligned(16))) ushort_t lds_k[64][136];
  __shared__ __attribute__((aligned(16))) ushort_t lds_vt[128][72];
  __shared__ __attribute__((aligned(16))) float p_lds[4][16][68];

  int kr = tid >> 2, kc = (tid & 3) * 32;
  int vd = tid >> 1, vj = (tid & 1) * 32;
  const ushort_t* kg = Kb + (size_t)kr * KVDIM + kvh * HD + kc;
  const ushort_t* vg = Vt + (size_t)kvh * (HD * SEQ) + (size_t)vd * SEQ + vj;

#pragma unroll 1
  for (int ph = 0; ph < 2; ++ph) {
    int qb = ph ? (31 - blockIdx.x) : blockIdx.x;
    int q0 = qb * 64 + w * 16;

    bf16x8 qf[4];
    const ushort_t* qp = Q + (size_t)(q0 + row) * DIM + h * HD + quad * 8;
#pragma unroll
    for (int ks = 0; ks < 4; ++ks) qf[ks] = *(const bf16x8*)(qp + ks * 32);

    floatx4 o_acc[8] = {};
    float l_r[4] = {0.f, 0.f, 0.f, 0.f};

    for (int kt = 0; kt <= qb; ++kt) {
      int kv0 = kt * 64;
#pragma unroll
      for (int e = 0; e < 4; ++e)
        *(bf16x8*)&lds_k[kr][kc + e * 8] = *(const bf16x8*)(kg + (size_t)kv0 * KVDIM + e * 8);
#pragma unroll
      for (int e = 0; e < 4; ++e)
        *(bf16x8*)&lds_vt[vd][vj + e * 8] = *(const bf16x8*)(vg + kv0 + e * 8);
      __syncthreads();

      floatx4 s[4] = {};
#pragma unroll
      for (int j2 = 0; j2 < 4; ++j2)
#pragma unroll
        for (int ks = 0; ks < 4; ++ks) {
          bf16x8 kfrag = *(const bf16x8*)&lds_k[j2 * 16 + row][ks * 32 + quad * 8];
          s[j2] = __builtin_amdgcn_mfma_f32_16x16x32_bf16(qf[ks], kfrag, s[j2], 0, 0, 0);
        }

      bool diag = (kt == qb);
      float pv[4][4];
#pragma unroll
      for (int j2 = 0; j2 < 4; ++j2)
#pragma unroll
        for (int r = 0; r < 4; ++r) {
          float v = s[j2][r];
          if (diag) {
            int j_g = kv0 + j2 * 16 + row;
            int i_g = q0 + quad * 4 + r;
            v += (j_g <= i_g) ? 0.f : -1e9f;
          }
          float p = exp2f(v);
          pv[j2][r] = p;
          l_r[r] += p;
        }
#pragma unroll
      for (int j2 = 0; j2 < 4; ++j2)
#pragma unroll
        for (int r = 0; r < 4; ++r) p_lds[w][quad * 4 + r][j2 * 16 + row] = pv[j2][r];
      bf16x8 pf[2];
#pragma unroll
      for (int kb2 = 0; kb2 < 2; ++kb2) {
        float4 pa = *(const float4*)&p_lds[w][row][kb2 * 32 + quad * 8];
        float4 pb = *(const float4*)&p_lds[w][row][kb2 * 32 + quad * 8 + 4];
        union { bf16x8 v; ushort_t u[8]; } pu;
        pu.u[0] = f2b(pa.x); pu.u[1] = f2b(pa.y); pu.u[2] = f2b(pa.z); pu.u[3] = f2b(pa.w);
        pu.u[4] = f2b(pb.x); pu.u[5] = f2b(pb.y); pu.u[6] = f2b(pb.z); pu.u[7] = f2b(pb.w);
        pf[kb2] = pu.v;
      }
#pragma unroll
      for (int db = 0; db < 8; ++db)
#pragma unroll
        for (int kb2 = 0; kb2 < 2; ++kb2) {
          bf16x8 vfrag = *(const bf16x8*)&lds_vt[db * 16 + row][kb2 * 32 + quad * 8];
          o_acc[db] = __builtin_amdgcn_mfma_f32_16x16x32_bf16(pf[kb2], vfrag, o_acc[db], 0, 0, 0);
        }
      __syncthreads();
    }

#pragma unroll
    for (int off = 1; off < 16; off <<= 1)
#pragma unroll
      for (int r = 0; r < 4; ++r) l_r[r] += __shfl_xor(l_r[r], off, 64);
    float inv[4];
#pragma unroll
    for (int r = 0; r < 4; ++r) inv[r] = 1.0f / l_r[r];
#pragma unroll
    for (int db = 0; db < 8; ++db)
#pragma unroll
      for (int r = 0; r < 4; ++r)
        O[(size_t)(q0 + quad * 4 + r) * DIM + h * HD + db * 16 + row] = f2b(o_acc[db][r] * inv[r]);
  }
}

extern "C" void kernel_launch(void* const* d_in, const int* in_sizes, int n_in,
                              void* d_out, int out_size, void* d_ws, size_t ws_size,
                              hipStream_t stream) {
  const float* x    = (const float*)d_in[0];
  const float* cosf = (const float*)d_in[1];
  const float* sinf = (const float*)d_in[2];
  const float* wq = (const float*)d_in[7];
  const float* wk = (const float*)d_in[8];
  const float* wv = (const float*)d_in[9];
  const float* wo = (const float*)d_in[10];
  float* out = (float*)d_out;
  float* cache_v_out = out + 12582912;

  char* ws = (char*)d_ws;
  ushort_t* xb     = (ushort_t*)(ws + 0);          // 16.8 MB
  ushort_t* wqkvb  = (ushort_t*)(ws + 16777216);   // 50.3 MB (wq|wk|wv rows)
  ushort_t* wob    = (ushort_t*)(ws + 67108864);   // 33.6 MB
  float*    qkv32  = (float*)(ws + 100663296);     // 50.3 MB
  ushort_t* qbuf   = (ushort_t*)(ws + 150994944);  // 16.8 MB
  ushort_t* kbuf   = (ushort_t*)(ws + 167772160);  // 4.2 MB
  ushort_t* vtb    = (ushort_t*)(ws + 171966464);  // 4.2 MB
  ushort_t* attnb  = (ushort_t*)(ws + 176160768);  // 16.8 MB -> 192.9 MB total

  // 1. all converts in one launch
  cvt_all<<<24576, 256, 0, stream>>>(x, wq, wk, wv, wo, xb, wqkvb, wob);
  // 2. fused QKV projection (2048 x 6144 x 4096): 8m x 48n = 384 blocks
  gemm2p<<<384, 512, 0, stream>>>(xb, wqkvb, qkv32, QKVN, DIM);
  // 3. rope_q + rope_k/cache_k + zero tails in one launch; V transpose separate
  posteps<<<22528, 256, 0, stream>>>(qkv32, cosf, sinf, qbuf, kbuf, out);
  vt_cache<<<dim3(32, 16), 256, 0, stream>>>(qkv32, vtb, cache_v_out);
  // 4. attention (pair-balanced grid)
  attn<<<dim3(16, 32), 256, 0, stream>>>(qbuf, kbuf, vtb, attnb);
  // 5. output projection (2048 x 4096 x 4096): 8m x 32n = 256 blocks = 1/CU
  gemm2p<<<256, 512, 0, stream>>>(attnb, wob, out, DIM, DIM);
}

// Round 3
// 561.252 us; speedup vs baseline: 1.0650x; 1.0650x over previous
//
#include <hip/hip_runtime.h>

typedef unsigned short ushort_t;
typedef unsigned int uint_t;
typedef __attribute__((ext_vector_type(8))) short bf16x8;
typedef __attribute__((ext_vector_type(4))) float floatx4;

#define SEQ 2048
#define DIM 4096
#define NH 32
#define NKV 8
#define HD 128
#define KVDIM 1024
#define QKVN 6144  // DIM + 2*KVDIM

__device__ __forceinline__ ushort_t f2b(float f) {
  union { float f; uint_t u; } x; x.f = f;
  uint_t u = x.u;
  u += 0x7fffu + ((u >> 16) & 1u);  // round-to-nearest-even
  return (ushort_t)(u >> 16);
}

#define GLOAD_LDS(g, l) \
  __builtin_amdgcn_global_load_lds((const __attribute__((address_space(1))) void*)(g), \
                                   (__attribute__((address_space(3))) void*)(l), 16, 0, 0)

#define BARX() asm volatile("s_barrier" ::: "memory")
#define WAIT_VM(n) asm volatile("s_waitcnt vmcnt(" #n ")" ::: "memory")
#define LGKM0() asm volatile("s_waitcnt lgkmcnt(0)" ::: "memory")

// ---------------- all f32 -> bf16 converts in one kernel ----------------
__global__ __launch_bounds__(256) void cvt_all(const float* __restrict__ x,
                                               const float* __restrict__ wq,
                                               const float* __restrict__ wk,
                                               const float* __restrict__ wv,
                                               const float* __restrict__ wo,
                                               ushort_t* __restrict__ xb,
                                               ushort_t* __restrict__ wqkvb,
                                               ushort_t* __restrict__ wob) {
  int b = blockIdx.x;
  const float* src; ushort_t* dst; int i;
  if (b < 4096)       { src = x;  dst = xb;               i = b * 256 + threadIdx.x; }
  else if (b < 12288) { src = wq; dst = wqkvb;            i = (b - 4096) * 256 + threadIdx.x; }
  else if (b < 14336) { src = wk; dst = wqkvb + 16777216; i = (b - 12288) * 256 + threadIdx.x; }
  else if (b < 16384) { src = wv; dst = wqkvb + 20971520; i = (b - 14336) * 256 + threadIdx.x; }
  else                { src = wo; dst = wob;              i = (b - 16384) * 256 + threadIdx.x; }
  const float4* s = (const float4*)src;
  float4 a = s[2 * i], c = s[2 * i + 1];
  union { ushort_t u[8]; uint4 v; } o;
  o.u[0] = f2b(a.x); o.u[1] = f2b(a.y); o.u[2] = f2b(a.z); o.u[3] = f2b(a.w);
  o.u[4] = f2b(c.x); o.u[5] = f2b(c.y); o.u[6] = f2b(c.z); o.u[7] = f2b(c.w);
  ((uint4*)dst)[i] = o.v;
}

// ---------------- bf16 GEMM: C f32[M][N] = A[M][K] * B[N][K]^T ----------------
// BM=256, BN=BNT (128 or 192), BK=64. 512 threads = 8 waves (4M x 2N),
// wave tile 64 x (BNT/2). 2 phases per K-tile, 4*(CGN/2)*2 MFMA per phase.
// LDS: double-buffered A(256x64) + B(BNTx64), chunk^(row&7) swizzle.
// Schedule identical to the r2 gemm2p (proven on the 256-block O-proj):
//   ph1u: read slot0 A(all)+B[0..CGH) | stage B(v)   -> slot1-B
//   ph2u: read slot0 B[CGH..CGN)      | stage A(u+2) -> slot0-A  | vmcnt(4)
//   ph1v: read slot1 A(all)+B[0..CGH) | stage B(u+2) -> slot0-B
//   ph2v: read slot1 B[CGH..CGN)      | stage A(v+2) -> slot1-A  | vmcnt(4)
// In-flight queue at each WAIT_VM(4): [A:4][B:UB][A:4] -> keeping last 4
// drains exactly the tile needed next. Works for UB=2 and UB=3.
template<int BNT>
__global__ __launch_bounds__(512, 2) void gemm2p(const ushort_t* __restrict__ A,
                                                 const ushort_t* __restrict__ B,
                                                 float* __restrict__ C,
                                                 int N, int K) {
  constexpr int CGN = BNT / 32;   // B frag columns per wave (4 or 6)
  constexpr int CGH = CGN / 2;    // phase split (2 or 3)
  constexpr int UB  = BNT / 64;   // B 64-row staging units (2 or 3)
  constexpr int WNT = BNT / 2;    // wave tile N (64 or 96)

  __shared__ __attribute__((aligned(16))) ushort_t sA[2][16384];     // 256 rows x 64
  __shared__ __attribute__((aligned(16))) ushort_t sB[2][BNT * 64];  // BNT rows x 64

  int tid = threadIdx.x;
  int lane = tid & 63;
  int w = tid >> 6;
  int wm = w >> 1, wn = w & 1;          // 4M x 2N waves
  int l15 = lane & 15, l4 = lane >> 4;
  int co0 = (l4 ^ (l15 & 7)) << 3;      // swizzled frag elem offset, ks=0
  int co1 = co0 ^ 32;                   // ks=1 (chunk^4)

  // XCD swizzle, n-major: each XCD gets all 8 m-tiles x contiguous n-tiles.
  int nblk = (int)gridDim.x;            // 256 for both launches
  int lin = ((int)blockIdx.x & 7) * (nblk >> 3) + ((int)blockIdx.x >> 3);
  int m0 = (lin & 7) << 8;
  int n0 = (lin >> 3) * BNT;

  int nkt = K >> 6;
  int niter = nkt >> 1;

  // staging: 1 gload/thread per 64-row unit; LDS linear, global col pre-swizzled
  int r0 = tid >> 3;
  int cg8 = ((tid & 7) ^ (r0 & 7)) << 3;
  const ushort_t* sa = A + (size_t)(m0 + r0) * K + cg8;
  const ushort_t* sb = B + (size_t)(n0 + r0) * K + cg8;
  int ldsb = (tid & ~63) << 3;          // wave-uniform elem offset within unit
  size_t rK = (size_t)64 * K;           // 64-row global stride

#define SUA(s, k0) do { _Pragma("unroll") for (int uu = 0; uu < 4; ++uu) \
    GLOAD_LDS(sa + (size_t)uu * rK + (k0), &sA[s][uu * 4096 + ldsb]); } while (0)
#define SUB(s, k0) do { _Pragma("unroll") for (int uu = 0; uu < UB; ++uu) \
    GLOAD_LDS(sb + (size_t)uu * rK + (k0), &sB[s][uu * 4096 + ldsb]); } while (0)

  floatx4 acc[4][CGN] = {};
  bf16x8 a[4][2], b[CGN][2];

#define RDA(s) do { const ushort_t* pa = &sA[s][(wm * 64 + l15) * 64]; \
  _Pragma("unroll") for (int rg = 0; rg < 4; ++rg) { \
    a[rg][0] = *(const bf16x8*)&pa[rg * 1024 + co0]; \
    a[rg][1] = *(const bf16x8*)&pa[rg * 1024 + co1]; } } while (0)
#define RDB(s, C0, C1) do { const ushort_t* pb = &sB[s][(wn * WNT + l15) * 64]; \
  _Pragma("unroll") for (int cg = C0; cg < C1; ++cg) { \
    b[cg][0] = *(const bf16x8*)&pb[cg * 1024 + co0]; \
    b[cg][1] = *(const bf16x8*)&pb[cg * 1024 + co1]; } } while (0)

#define QUAD(C0, C1) do { __builtin_amdgcn_s_setprio(1); \
  _Pragma("unroll") for (int rg = 0; rg < 4; ++rg) \
  _Pragma("unroll") for (int cg = C0; cg < C1; ++cg) \
  _Pragma("unroll") for (int ks = 0; ks < 2; ++ks) \
    acc[rg][cg] = __builtin_amdgcn_mfma_f32_16x16x32_bf16( \
        a[rg][ks], b[cg][ks], acc[rg][cg], 0, 0, 0); \
  __builtin_amdgcn_s_setprio(0); } while (0)

  // prologue: tile0 {A,B} -> slot0 (4+UB), tile1 {A} -> slot1 (4); wait tile0
  SUA(0, 0); SUB(0, 0);
  SUA(1, 64);
  WAIT_VM(4);
  BARX();

#pragma unroll 1
  for (int i = 0; i < niter; ++i) {
    int kv = (2 * i + 1) << 6;
    int tu2 = 2 * i + 2; if (tu2 > nkt - 1) tu2 = nkt - 1;  // clamped overrun stages
    int tv2 = 2 * i + 3; if (tv2 > nkt - 1) tv2 = nkt - 1;  // land in freed regions
    int ku2 = tu2 << 6, kv2 = tv2 << 6;

    // ph1u
    RDA(0); RDB(0, 0, CGH);
    SUB(1, kv);
    BARX(); LGKM0();
    QUAD(0, CGH);
    BARX();
    // ph2u
    RDB(0, CGH, CGN);
    SUA(0, ku2);
    BARX(); LGKM0();
    QUAD(CGH, CGN);
    WAIT_VM(4);
    BARX();
    // ph1v
    RDA(1); RDB(1, 0, CGH);
    SUB(0, ku2);
    BARX(); LGKM0();
    QUAD(0, CGH);
    BARX();
    // ph2v
    RDB(1, CGH, CGN);
    SUA(1, kv2);
    BARX(); LGKM0();
    QUAD(CGH, CGN);
    WAIT_VM(4);
    BARX();
  }

  // epilogue: C/D layout col=lane&15, row=(lane>>4)*4+reg
#pragma unroll
  for (int rg = 0; rg < 4; ++rg)
#pragma unroll
    for (int cg = 0; cg < CGN; ++cg) {
      float* cp = C + (size_t)(m0 + wm * 64 + rg * 16 + l4 * 4) * N
                    + (n0 + wn * WNT + cg * 16 + l15);
#pragma unroll
      for (int r = 0; r < 4; ++r) cp[(size_t)r * N] = acc[rg][cg][r];
    }
#undef SUA
#undef SUB
#undef RDA
#undef RDB
#undef QUAD
}

// ---------------- rope_q + rope_k + zero_tail fused (branch by block) ----------------
__global__ __launch_bounds__(256) void posteps(const float* __restrict__ qkv,
                                               const float* __restrict__ cosf,
                                               const float* __restrict__ sinf,
                                               ushort_t* __restrict__ qb,
                                               ushort_t* __restrict__ kb,
                                               float* __restrict__ out) {
  int b = blockIdx.x;
  if (b < 16384) {  // rope_q, pre-scaled by log2(e)/sqrt(128)
    const float QS = 1.4426950408889634f * 0.08838834764831845f;
    int idx = b * 256 + threadIdx.x;
    int pos = idx >> 11;
    int p = idx & 2047;
    int h = p >> 6, i = p & 63;
    size_t sb = (size_t)pos * QKVN + h * HD + 2 * i;
    float x1 = qkv[sb], x2 = qkv[sb + 1];
    float c = cosf[pos * 64 + i], s = sinf[pos * 64 + i];
    float r1 = (x1 * c - x2 * s) * QS;
    float r2 = (x1 * s + x2 * c) * QS;
    size_t db = (size_t)pos * DIM + h * HD + 2 * i;
    ((uint_t*)qb)[db >> 1] = (uint_t)f2b(r1) | ((uint_t)f2b(r2) << 16);
  } else if (b < 20480) {  // rope_k + cache_k
    int idx = (b - 16384) * 256 + threadIdx.x;
    int pos = idx >> 9;
    int p = idx & 511;
    int kvh = p >> 6, i = p & 63;
    size_t sb = (size_t)pos * QKVN + DIM + kvh * HD + 2 * i;
    float x1 = qkv[sb], x2 = qkv[sb + 1];
    float c = cosf[pos * 64 + i], s = sinf[pos * 64 + i];
    float r1 = x1 * c - x2 * s;
    float r2 = x1 * s + x2 * c;
    size_t db = (size_t)pos * KVDIM + kvh * HD + 2 * i;
    ((uint_t*)kb)[db >> 1] = (uint_t)f2b(r1) | ((uint_t)f2b(r2) << 16);
    float2 cv; cv.x = r1; cv.y = r2;
    ((float2*)(out + 8388608))[db >> 1] = cv;  // cache_k base
  } else {  // zero tails of both caches
    int i = (b - 20480) * 256 + threadIdx.x;
    float4 z = {0.f, 0.f, 0.f, 0.f};
    ((float4*)(out + 10485760))[i] = z;  // cache_k rows 2048..4095
    ((float4*)(out + 14680064))[i] = z;  // cache_v rows 2048..4095
  }
}

// ---------------- V: cache_v f32 copy + transposed bf16 Vt[kvh][d][pos] ----------------
__global__ __launch_bounds__(256) void vt_cache(const float* __restrict__ qkv,
                                                ushort_t* __restrict__ vtb,
                                                float* __restrict__ cache_v) {
  __shared__ float tile[64][65];
  int pos0 = blockIdx.x * 64, c0 = blockIdx.y * 64;
  int t = threadIdx.x;
  int pr = t >> 4, cq = (t & 15) * 4;
#pragma unroll
  for (int rr = 0; rr < 4; ++rr) {
    int prow = pr + rr * 16;
    float4 v = *(const float4*)(qkv + (size_t)(pos0 + prow) * QKVN + DIM + KVDIM + c0 + cq);
    *(float4*)(cache_v + (size_t)(pos0 + prow) * KVDIM + c0 + cq) = v;
    tile[prow][cq] = v.x; tile[prow][cq + 1] = v.y;
    tile[prow][cq + 2] = v.z; tile[prow][cq + 3] = v.w;
  }
  __syncthreads();
  int dc = t >> 2, pg = (t & 3) * 16;
  int kvh = c0 >> 7, dl = (c0 & 127) + dc;
  union { ushort_t u[16]; uint4 q[2]; } o;
#pragma unroll
  for (int e = 0; e < 16; ++e) o.u[e] = f2b(tile[pg + e][dc]);
  uint4* dst = (uint4*)(vtb + (size_t)kvh * (HD * SEQ) + (size_t)dl * SEQ + pos0 + pg);
  dst[0] = o.q[0]; dst[1] = o.q[1];
}

// ---------------- flash attention: causal, GQA 4:1, pair-balanced ----------------
__global__ __launch_bounds__(256) void attn(const ushort_t* __restrict__ Q,
                                            const ushort_t* __restrict__ Kb,
                                            const ushort_t* __restrict__ Vt,
                                            ushort_t* __restrict__ O) {
  int h = blockIdx.y;
  int kvh = h >> 2;
  int tid = threadIdx.x;
  int w = tid >> 6, lane = tid & 63;
  int row = lane & 15, quad = lane >> 4;

  __shared__ __attribute__((aligned(16))) ushort_t lds_k[64][136];
  __shared__ __attribute__((aligned(16))) ushort_t lds_vt[128][72];
  __shared__ __attribute__((aligned(16))) float p_lds[4][16][68];

  int kr = tid >> 2, kc = (tid & 3) * 32;
  int vd = tid >> 1, vj = (tid & 1) * 32;
  const ushort_t* kg = Kb + (size_t)kr * KVDIM + kvh * HD + kc;
  const ushort_t* vg = Vt + (size_t)kvh * (HD * SEQ) + (size_t)vd * SEQ + vj;

#pragma unroll 1
  for (int ph = 0; ph < 2; ++ph) {
    int qb = ph ? (31 - blockIdx.x) : blockIdx.x;
    int q0 = qb * 64 + w * 16;

    bf16x8 qf[4];
    const ushort_t* qp = Q + (size_t)(q0 + row) * DIM + h * HD + quad * 8;
#pragma unroll
    for (int ks = 0; ks < 4; ++ks) qf[ks] = *(const bf16x8*)(qp + ks * 32);

    floatx4 o_acc[8] = {};
    float l_r[4] = {0.f, 0.f, 0.f, 0.f};

    for (int kt = 0; kt <= qb; ++kt) {
      int kv0 = kt * 64;
#pragma unroll
      for (int e = 0; e < 4; ++e)
        *(bf16x8*)&lds_k[kr][kc + e * 8] = *(const bf16x8*)(kg + (size_t)kv0 * KVDIM + e * 8);
#pragma unroll
      for (int e = 0; e < 4; ++e)
        *(bf16x8*)&lds_vt[vd][vj + e * 8] = *(const bf16x8*)(vg + kv0 + e * 8);
      __syncthreads();

      floatx4 s[4] = {};
#pragma unroll
      for (int j2 = 0; j2 < 4; ++j2)
#pragma unroll
        for (int ks = 0; ks < 4; ++ks) {
          bf16x8 kfrag = *(const bf16x8*)&lds_k[j2 * 16 + row][ks * 32 + quad * 8];
          s[j2] = __builtin_amdgcn_mfma_f32_16x16x32_bf16(qf[ks], kfrag, s[j2], 0, 0, 0);
        }

      bool diag = (kt == qb);
      float pv[4][4];
#pragma unroll
      for (int j2 = 0; j2 < 4; ++j2)
#pragma unroll
        for (int r = 0; r < 4; ++r) {
          float v = s[j2][r];
          if (diag) {
            int j_g = kv0 + j2 * 16 + row;
            int i_g = q0 + quad * 4 + r;
            v += (j_g <= i_g) ? 0.f : -1e9f;
          }
          float p = exp2f(v);
          pv[j2][r] = p;
          l_r[r] += p;
        }
#pragma unroll
      for (int j2 = 0; j2 < 4; ++j2)
#pragma unroll
        for (int r = 0; r < 4; ++r) p_lds[w][quad * 4 + r][j2 * 16 + row] = pv[j2][r];
      bf16x8 pf[2];
#pragma unroll
      for (int kb2 = 0; kb2 < 2; ++kb2) {
        float4 pa = *(const float4*)&p_lds[w][row][kb2 * 32 + quad * 8];
        float4 pb = *(const float4*)&p_lds[w][row][kb2 * 32 + quad * 8 + 4];
        union { bf16x8 v; ushort_t u[8]; } pu;
        pu.u[0] = f2b(pa.x); pu.u[1] = f2b(pa.y); pu.u[2] = f2b(pa.z); pu.u[3] = f2b(pa.w);
        pu.u[4] = f2b(pb.x); pu.u[5] = f2b(pb.y); pu.u[6] = f2b(pb.z); pu.u[7] = f2b(pb.w);
        pf[kb2] = pu.v;
      }
#pragma unroll
      for (int db = 0; db < 8; ++db)
#pragma unroll
        for (int kb2 = 0; kb2 < 2; ++kb2) {
          bf16x8 vfrag = *(const bf16x8*)&lds_vt[db * 16 + row][kb2 * 32 + quad * 8];
          o_acc[db] = __builtin_amdgcn_mfma_f32_16x16x32_bf16(pf[kb2], vfrag, o_acc[db], 0, 0, 0);
        }
      __syncthreads();
    }

#pragma unroll
    for (int off = 1; off < 16; off <<= 1)
#pragma unroll
      for (int r = 0; r < 4; ++r) l_r[r] += __shfl_xor(l_r[r], off, 64);
    float inv[4];
#pragma unroll
    for (int r = 0; r < 4; ++r) inv[r] = 1.0f / l_r[r];
#pragma unroll
    for (int db = 0; db < 8; ++db)
#pragma unroll
      for (int r = 0; r < 4; ++r)
        O[(size_t)(q0 + quad * 4 + r) * DIM + h * HD + db * 16 + row] = f2b(o_acc[db][r] * inv[r]);
  }
}

extern "C" void kernel_launch(void* const* d_in, const int* in_sizes, int n_in,
                              void* d_out, int out_size, void* d_ws, size_t ws_size,
                              hipStream_t stream) {
  const float* x    = (const float*)d_in[0];
  const float* cosf = (const float*)d_in[1];
  const float* sinf = (const float*)d_in[2];
  const float* wq = (const float*)d_in[7];
  const float* wk = (const float*)d_in[8];
  const float* wv = (const float*)d_in[9];
  const float* wo = (const float*)d_in[10];
  float* out = (float*)d_out;
  float* cache_v_out = out + 12582912;

  char* ws = (char*)d_ws;
  ushort_t* xb     = (ushort_t*)(ws + 0);          // 16.8 MB
  ushort_t* wqkvb  = (ushort_t*)(ws + 16777216);   // 50.3 MB (wq|wk|wv rows)
  ushort_t* wob    = (ushort_t*)(ws + 67108864);   // 33.6 MB
  float*    qkv32  = (float*)(ws + 100663296);     // 50.3 MB
  ushort_t* qbuf   = (ushort_t*)(ws + 150994944);  // 16.8 MB
  ushort_t* kbuf   = (ushort_t*)(ws + 167772160);  // 4.2 MB
  ushort_t* vtb    = (ushort_t*)(ws + 171966464);  // 4.2 MB
  ushort_t* attnb  = (ushort_t*)(ws + 176160768);  // 16.8 MB -> 192.9 MB total

  // 1. all converts in one launch
  cvt_all<<<24576, 256, 0, stream>>>(x, wq, wk, wv, wo, xb, wqkvb, wob);
  // 2. fused QKV projection (2048 x 6144 x 4096): BN=192 -> 8m x 32n = 256 blocks = 1/CU
  gemm2p<192><<<256, 512, 0, stream>>>(xb, wqkvb, qkv32, QKVN, DIM);
  // 3. rope_q + rope_k/cache_k + zero tails in one launch; V transpose separate
  posteps<<<22528, 256, 0, stream>>>(qkv32, cosf, sinf, qbuf, kbuf, out);
  vt_cache<<<dim3(32, 16), 256, 0, stream>>>(qkv32, vtb, cache_v_out);
  // 4. attention (pair-balanced grid)
  attn<<<dim3(16, 32), 256, 0, stream>>>(qbuf, kbuf, vtb, attnb);
  // 5. output projection (2048 x 4096 x 4096): BN=128 -> 8m x 32n = 256 blocks = 1/CU
  gemm2p<128><<<256, 512, 0, stream>>>(attnb, wob, out, DIM, DIM);
}